// Round 6
// baseline (403.046 us; speedup 1.0000x reference)
//
#include <hip/hip_runtime.h>
#include <stdint.h>

#define BSZ 16
#define TT  2048
#define NSEM 2048
#define DIM 128
#define ORS 1024          // shorts per output row (512 floats)
#define PSTR 68           // pbuf row stride in shorts

typedef __attribute__((ext_vector_type(8))) short short8;
typedef __attribute__((ext_vector_type(4))) float floatx4;

__device__ __forceinline__ unsigned short f2bf(float f){       // RNE
  unsigned u = __float_as_uint(f);
  return (unsigned short)((u + 0x7fffu + ((u >> 16) & 1u)) >> 16);
}
__device__ __forceinline__ void ld8f(const float* p, float* v){
  floatx4 a = *(const floatx4*)p;
  floatx4 b = *(const floatx4*)(p + 4);
  v[0]=a[0]; v[1]=a[1]; v[2]=a[2]; v[3]=a[3];
  v[4]=b[0]; v[5]=b[1]; v[6]=b[2]; v[7]=b[3];
}

// ---------------- kernel 1: prep (unchanged, verified round 5) ----------------
__global__ __launch_bounds__(256) void prep_kernel(const float* __restrict__ sem,
                                                   const float* __restrict__ W,
                                                   float* __restrict__ colB,
                                                   unsigned short* __restrict__ outw){
  __shared__ unsigned short tile[DIM * 72];
  const int tid = threadIdx.x;
  const int b  = blockIdx.x >> 5;
  const int n0 = (blockIdx.x & 31) * 64;

  const int r = tid >> 2, cc = tid & 3, c = cc * 32;
  const float* src = sem + ((size_t)(b * NSEM + n0 + r)) * DIM + c;
  float v[32];
  ld8f(src, v); ld8f(src + 8, v + 8); ld8f(src + 16, v + 16); ld8f(src + 24, v + 24);
  alignas(16) unsigned short bf[32];
  float cpart = 0.f;
  #pragma unroll
  for (int j = 0; j < 32; ++j){
    bf[j] = f2bf(v[j]);
    cpart += v[j] * W[DIM + c + j];
  }
  {
    unsigned short* dst = outw + ((size_t)(b * TT + n0 + r)) * ORS + c;
    const uint4* s4 = (const uint4*)bf;
    *(uint4*)(dst) = s4[0]; *(uint4*)(dst+8) = s4[1];
    *(uint4*)(dst+16) = s4[2]; *(uint4*)(dst+24) = s4[3];
  }
  #pragma unroll
  for (int j = 0; j < 32; ++j) tile[(c + j) * 72 + r] = bf[j];
  cpart += __shfl_xor(cpart, 1);
  cpart += __shfl_xor(cpart, 2);
  if (cc == 0) colB[b * NSEM + n0 + r] = cpart;
  __syncthreads();

  const int d = tid >> 1, nh = (tid & 1) * 32;
  uint4 t0v = *(const uint4*)&tile[d * 72 + nh];
  uint4 t1v = *(const uint4*)&tile[d * 72 + nh + 8];
  uint4 t2v = *(const uint4*)&tile[d * 72 + nh + 16];
  uint4 t3v = *(const uint4*)&tile[d * 72 + nh + 24];
  const int n = n0 + nh;
  const int piece = n >> 9;
  unsigned short* dst = outw + ((size_t)(b * TT + d * 4 + piece)) * ORS + 512 + (n & 511);
  *(uint4*)(dst) = t0v; *(uint4*)(dst+8) = t1v;
  *(uint4*)(dst+16) = t2v; *(uint4*)(dst+24) = t3v;
}

// ---------------- kernel 2: flash, no-rescale softmax, 2-wave n-split ----------------
// grid = BSZ*128 blocks (b = bx>>7, t0 = (bx&127)*16), 128 thr = 2 waves.
// Wave wv covers n in [wv*1024, wv*1024+1024). Additive merge at end (exp is absolute).
__global__ __launch_bounds__(128, 4) void flash_kernel(const float* __restrict__ aud,
                                                       const float* __restrict__ W,
                                                       const float* __restrict__ colB,
                                                       float* __restrict__ m_ws,
                                                       float* __restrict__ outf,
                                                       const unsigned short* __restrict__ outw){
  __shared__ alignas(16) unsigned short pbuf[2][16 * PSTR];   // per-wave P staging
  __shared__ alignas(16) float obuf[16][132];                  // wave-1 partial O (padded)
  __shared__ float lmbuf[32];                                  // l[16], m[16]

  const int tid  = threadIdx.x;
  const int wv   = tid >> 6;
  const int lane = tid & 63;
  const int quad = lane >> 4;
  const int l15  = lane & 15;
  const int b    = blockIdx.x >> 7;
  const int t0   = (blockIdx.x & 127) * 16;

  // q A-frags (aud*w3 -> bf16) + rowA partial (fp32 dot aud,w1)
  const float* audRow = aud + ((size_t)b * TT + t0 + l15) * DIM;
  short8 qf[4];
  float rowA_part = 0.f;
  #pragma unroll
  for (int kc = 0; kc < 4; ++kc){
    int d0 = kc * 32 + quad * 8;
    float av[8], w3v[8], w1v[8];
    ld8f(audRow + d0, av);
    ld8f(W + 2 * DIM + d0, w3v);
    ld8f(W + d0, w1v);
    alignas(16) unsigned short tmp[8];
    #pragma unroll
    for (int j = 0; j < 8; ++j){
      tmp[j] = f2bf(av[j] * w3v[j]);
      rowA_part += av[j] * w1v[j];
    }
    qf[kc] = *(const short8*)tmp;
  }
  rowA_part += __shfl_xor(rowA_part, 16);
  rowA_part += __shfl_xor(rowA_part, 32);

  float m_l[4], l_l[4];
  floatx4 o[8];
  #pragma unroll
  for (int r = 0; r < 4; ++r){ m_l[r] = -1e30f; l_l[r] = 0.f; }
  #pragma unroll
  for (int dc = 0; dc < 8; ++dc){
    #pragma unroll
    for (int r = 0; r < 4; ++r) o[dc][r] = 0.f;
  }

  const unsigned short* semBF = outw + (size_t)b * TT * ORS;
  const float* colBb = colB + b * NSEM;
  unsigned short* pb = &pbuf[wv][0];
  const int nbeg = wv * 1024, nend = nbeg + 1024;

  for (int n0 = nbeg; n0 < nend; n0 += 64){
    // ---- QK: S = q . sem^T, 4 subtiles of 16 n ----
    floatx4 sacc[4];
    #pragma unroll
    for (int s = 0; s < 4; ++s){ sacc[s][0]=0.f; sacc[s][1]=0.f; sacc[s][2]=0.f; sacc[s][3]=0.f; }
    #pragma unroll
    for (int s = 0; s < 4; ++s){
      const unsigned short* kr = semBF + (size_t)(n0 + s*16 + l15) * ORS + quad * 8;
      #pragma unroll
      for (int kc = 0; kc < 4; ++kc){
        short8 kf = *(const short8*)(kr + kc * 32);
        sacc[s] = __builtin_amdgcn_mfma_f32_16x16x32_bf16(qf[kc], kf, sacc[s], 0, 0, 0);
      }
    }

    // ---- prefetch V-frags for kt=0 (overlaps the softmax VALU below) ----
    short8 vf0[8];
    {
      int nA = n0 + quad * 8;
      int pieceA = nA >> 9, ninA = nA & 511;
      #pragma unroll
      for (int dc = 0; dc < 8; ++dc)
        vf0[dc] = *(const short8*)(outw +
          ((size_t)(b * TT + (dc*16 + l15) * 4 + pieceA)) * ORS + 512 + ninA);
    }

    // ---- softmax (no rescale: e = exp(S), per-lane l/m accumulators) ----
    float cb[4];
    #pragma unroll
    for (int s = 0; s < 4; ++s) cb[s] = colBb[n0 + s*16 + l15];
    #pragma unroll
    for (int r = 0; r < 4; ++r){
      float v0 = sacc[0][r] + cb[0];
      float v1 = sacc[1][r] + cb[1];
      float v2 = sacc[2][r] + cb[2];
      float v3 = sacc[3][r] + cb[3];
      m_l[r] = fmaxf(m_l[r], fmaxf(fmaxf(v0, v1), fmaxf(v2, v3)));
      float e0 = __expf(v0), e1 = __expf(v1);
      float e2 = __expf(v2), e3 = __expf(v3);
      l_l[r] += (e0 + e1) + (e2 + e3);
      unsigned short* pr = pb + (quad*4 + r) * PSTR + l15;
      pr[0]  = f2bf(e0);
      pr[16] = f2bf(e1);
      pr[32] = f2bf(e2);
      pr[48] = f2bf(e3);
    }

    // wave-local LDS drain (DS pipe is in-order per wave; no block barrier needed)
    asm volatile("s_waitcnt lgkmcnt(0)" ::: "memory");
    short8 pf0 = *(const short8*)(pb + l15 * PSTR + quad * 8);
    short8 pf1 = *(const short8*)(pb + l15 * PSTR + 32 + quad * 8);

    // ---- PV: O += P . sem ----
    #pragma unroll
    for (int dc = 0; dc < 8; ++dc)
      o[dc] = __builtin_amdgcn_mfma_f32_16x16x32_bf16(pf0, vf0[dc], o[dc], 0, 0, 0);
    {
      int nB = n0 + 32 + quad * 8;
      int pieceB = nB >> 9, ninB = nB & 511;
      #pragma unroll
      for (int dc = 0; dc < 8; ++dc){
        short8 vf = *(const short8*)(outw +
          ((size_t)(b * TT + (dc*16 + l15) * 4 + pieceB)) * ORS + 512 + ninB);
        o[dc] = __builtin_amdgcn_mfma_f32_16x16x32_bf16(pf1, vf, o[dc], 0, 0, 0);
      }
    }
  }

  // ---- cross-lane reduce l/m within each quad (rows quad*4+r) ----
  #pragma unroll
  for (int r = 0; r < 4; ++r){
    float lv = l_l[r], mv = m_l[r];
    lv += __shfl_xor(lv, 1);  mv = fmaxf(mv, __shfl_xor(mv, 1));
    lv += __shfl_xor(lv, 2);  mv = fmaxf(mv, __shfl_xor(mv, 2));
    lv += __shfl_xor(lv, 4);  mv = fmaxf(mv, __shfl_xor(mv, 4));
    lv += __shfl_xor(lv, 8);  mv = fmaxf(mv, __shfl_xor(mv, 8));
    l_l[r] = lv; m_l[r] = mv;
  }

  // ---- merge wave 1 into wave 0 (additive; exp values are absolute) ----
  if (wv == 1){
    #pragma unroll
    for (int dc = 0; dc < 8; ++dc)
      #pragma unroll
      for (int r = 0; r < 4; ++r)
        obuf[quad*4 + r][dc*16 + l15] = o[dc][r];
    if (l15 == 0){
      #pragma unroll
      for (int r = 0; r < 4; ++r){
        lmbuf[quad*4 + r]      = l_l[r];
        lmbuf[16 + quad*4 + r] = m_l[r];
      }
    }
  }
  __syncthreads();
  if (wv == 0){
    #pragma unroll
    for (int r = 0; r < 4; ++r){
      l_l[r] += lmbuf[quad*4 + r];
      m_l[r] = fmaxf(m_l[r], lmbuf[16 + quad*4 + r]);
    }
    #pragma unroll
    for (int dc = 0; dc < 8; ++dc)
      #pragma unroll
      for (int r = 0; r < 4; ++r)
        o[dc][r] += obuf[quad*4 + r][dc*16 + l15];

    float rl[4];
    #pragma unroll
    for (int r = 0; r < 4; ++r) rl[r] = 1.0f / l_l[r];
    float* outB = outf + ((size_t)b * TT + t0) * 512 + 128;   // seg1
    #pragma unroll
    for (int dc = 0; dc < 8; ++dc)
      #pragma unroll
      for (int r = 0; r < 4; ++r)
        outB[(size_t)(quad*4 + r) * 512 + dc*16 + l15] = o[dc][r] * rl[r];

    float rAr[4];
    #pragma unroll
    for (int r = 0; r < 4; ++r) rAr[r] = __shfl(rowA_part, quad*4 + r);
    if (l15 == 0){
      #pragma unroll
      for (int r = 0; r < 4; ++r)
        m_ws[(size_t)b * TT + t0 + quad*4 + r] = m_l[r] + rAr[r];
    }
  }
}

// ---------------- kernel 3a: per-chunk max of m ----------------
__global__ __launch_bounds__(256) void bw1_kernel(const float* __restrict__ m_ws,
                                                  float* __restrict__ pmax){
  __shared__ float sA[4];
  const int b = blockIdx.x >> 3, ch = blockIdx.x & 7, tid = threadIdx.x;
  float v = m_ws[(size_t)b * TT + ch * 256 + tid];
  #pragma unroll
  for (int off = 1; off < 64; off <<= 1) v = fmaxf(v, __shfl_xor(v, off));
  if ((tid & 63) == 0) sA[tid >> 6] = v;
  __syncthreads();
  if (tid == 0)
    pmax[blockIdx.x] = fmaxf(fmaxf(sA[0], sA[1]), fmaxf(sA[2], sA[3]));
}

// ---------------- kernel 3b: partial exp-sum + partial a2 ----------------
__global__ __launch_bounds__(256) void bw2_kernel(const float* __restrict__ aud,
                                                  const float* __restrict__ m_ws,
                                                  const float* __restrict__ pmax,
                                                  float* __restrict__ gpart,
                                                  float* __restrict__ part){
  __shared__ float wbuf[256];
  __shared__ float red[16 * 128];
  __shared__ float gs4[4];
  const int b = blockIdx.x >> 3, ch = blockIdx.x & 7, tid = threadIdx.x;

  float gmax = pmax[b * 8];
  #pragma unroll
  for (int i = 1; i < 8; ++i) gmax = fmaxf(gmax, pmax[b * 8 + i]);

  float w = __expf(m_ws[(size_t)b * TT + ch * 256 + tid] - gmax);
  wbuf[tid] = w;
  float sm = w;
  #pragma unroll
  for (int off = 1; off < 64; off <<= 1) sm += __shfl_xor(sm, off);
  if ((tid & 63) == 0) gs4[tid >> 6] = sm;
  __syncthreads();
  if (tid == 0) gpart[blockIdx.x] = (gs4[0] + gs4[1]) + (gs4[2] + gs4[3]);

  const int dg = tid & 15, q = tid >> 4;
  float acc[8] = {0,0,0,0,0,0,0,0};
  const float* ab = aud + ((size_t)b * TT + ch * 256 + q * 16) * DIM + dg * 8;
  for (int i = 0; i < 16; ++i){
    float av[8];
    ld8f(ab + (size_t)i * DIM, av);
    float wt = wbuf[q * 16 + i];
    #pragma unroll
    for (int j = 0; j < 8; ++j) acc[j] += wt * av[j];
  }
  #pragma unroll
  for (int j = 0; j < 8; ++j) red[q * 128 + dg * 8 + j] = acc[j];
  __syncthreads();
  if (tid < 128){
    float s = 0.f;
    #pragma unroll
    for (int q2 = 0; q2 < 16; ++q2) s += red[q2 * 128 + tid];
    part[(size_t)blockIdx.x * 128 + tid] = s;
  }
}

// ---------------- kernel 3c: combine partials -> normalized a2 ----------------
__global__ __launch_bounds__(128) void bw3_kernel(const float* __restrict__ gpart,
                                                  const float* __restrict__ part,
                                                  float* __restrict__ a2_ws){
  const int b = blockIdx.x, d = threadIdx.x;
  float s = 0.f, g = 0.f;
  #pragma unroll
  for (int ch = 0; ch < 8; ++ch){
    s += part[(size_t)(b * 8 + ch) * 128 + d];
    g += gpart[b * 8 + ch];
  }
  a2_ws[b * DIM + d] = s / g;
}

// ---------------- kernel 4: read seg1 (h), write seg0/2/3 ----------------
__global__ __launch_bounds__(256) void epi_kernel(const float* __restrict__ aud,
                                                  const float* __restrict__ a2_ws,
                                                  float* __restrict__ out){
  int id = blockIdx.x * 256 + threadIdx.x;        // BSZ*TT*16
  int c = id & 15;
  int t = (id >> 4) & (TT - 1);
  int b = id >> 15;
  size_t row = (size_t)b * TT + t;

  float av[8], gv[8], hv[8];
  ld8f(aud + row * DIM + c * 8, av);
  ld8f(a2_ws + b * DIM + c * 8, gv);
  ld8f(out + row * 512 + 128 + c * 8, hv);        // h (seg1)

  floatx4 o0a, o0b, o2a, o2b, o3a, o3b;
  #pragma unroll
  for (int j = 0; j < 4; ++j){
    o0a[j] = av[j];           o0b[j] = av[4+j];
    o2a[j] = av[j]*hv[j];     o2b[j] = av[4+j]*hv[4+j];
    o3a[j] = av[j]*gv[j];     o3b[j] = av[4+j]*gv[4+j];
  }
  float* ob = out + row * 512 + c * 8;
  *(floatx4*)(ob)       = o0a;  *(floatx4*)(ob + 4)   = o0b;   // seg0: aud
  *(floatx4*)(ob + 256) = o2a;  *(floatx4*)(ob + 260) = o2b;   // seg2: aud*h
  *(floatx4*)(ob + 384) = o3a;  *(floatx4*)(ob + 388) = o3b;   // seg3: aud*a2
}

extern "C" void kernel_launch(void* const* d_in, const int* in_sizes, int n_in,
                              void* d_out, int out_size, void* d_ws, size_t ws_size,
                              hipStream_t stream){
  const float* aud = (const float*)d_in[0];   // fp32 inputs (verified round 4)
  const float* sem = (const float*)d_in[1];
  const float* W   = (const float*)d_in[2];
  // d_in[3] (bias) cancels in both softmaxes.
  float* out = (float*)d_out;                 // fp32 output (verified round 4)
  unsigned short* outw = (unsigned short*)d_out;

  float* ws    = (float*)d_ws;
  float* m_ws  = ws;                                   // 32768 f (128 KB)
  float* colB  = m_ws + (size_t)BSZ * TT;              // 32768 f (128 KB)
  float* a2_ws = colB + (size_t)BSZ * NSEM;            // 2048 f  (8 KB)
  float* pmax  = a2_ws + BSZ * DIM;                    // 128 f
  float* gpart = pmax + 128;                           // 128 f
  float* part  = gpart + 128;                          // 16384 f (64 KB)

  prep_kernel <<<512, 256, 0, stream>>>(sem, W, colB, outw);
  flash_kernel<<<BSZ * 128, 128, 0, stream>>>(aud, W, colB, m_ws, out, outw);
  bw1_kernel  <<<128, 256, 0, stream>>>(m_ws, pmax);
  bw2_kernel  <<<128, 256, 0, stream>>>(aud, m_ws, pmax, gpart, part);
  bw3_kernel  <<<BSZ, 128, 0, stream>>>(gpart, part, a2_ws);
  epi_kernel  <<<(BSZ * TT * 16) / 256, 256, 0, stream>>>(aud, a2_ws, out);
}

// Round 7
// 378.480 us; speedup vs baseline: 1.0649x; 1.0649x over previous
//
#include <hip/hip_runtime.h>
#include <stdint.h>

#define BSZ 16
#define TT  2048
#define NSEM 2048
#define DIM 128
#define ORS 1024          // shorts per output row (512 floats)
#define PSTR 68           // pbuf row stride in shorts

typedef __attribute__((ext_vector_type(8))) short short8;
typedef __attribute__((ext_vector_type(4))) float floatx4;

__device__ __forceinline__ unsigned short f2bf(float f){       // RNE
  unsigned u = __float_as_uint(f);
  return (unsigned short)((u + 0x7fffu + ((u >> 16) & 1u)) >> 16);
}
__device__ __forceinline__ void ld8f(const float* p, float* v){
  floatx4 a = *(const floatx4*)p;
  floatx4 b = *(const floatx4*)(p + 4);
  v[0]=a[0]; v[1]=a[1]; v[2]=a[2]; v[3]=a[3];
  v[4]=b[0]; v[5]=b[1]; v[6]=b[2]; v[7]=b[3];
}

// ---------------- kernel 1: prep (unchanged, verified round 5) ----------------
__global__ __launch_bounds__(256) void prep_kernel(const float* __restrict__ sem,
                                                   const float* __restrict__ W,
                                                   float* __restrict__ colB,
                                                   unsigned short* __restrict__ outw){
  __shared__ unsigned short tile[DIM * 72];
  const int tid = threadIdx.x;
  const int b  = blockIdx.x >> 5;
  const int n0 = (blockIdx.x & 31) * 64;

  const int r = tid >> 2, cc = tid & 3, c = cc * 32;
  const float* src = sem + ((size_t)(b * NSEM + n0 + r)) * DIM + c;
  float v[32];
  ld8f(src, v); ld8f(src + 8, v + 8); ld8f(src + 16, v + 16); ld8f(src + 24, v + 24);
  alignas(16) unsigned short bf[32];
  float cpart = 0.f;
  #pragma unroll
  for (int j = 0; j < 32; ++j){
    bf[j] = f2bf(v[j]);
    cpart += v[j] * W[DIM + c + j];
  }
  {
    unsigned short* dst = outw + ((size_t)(b * TT + n0 + r)) * ORS + c;
    const uint4* s4 = (const uint4*)bf;
    *(uint4*)(dst) = s4[0]; *(uint4*)(dst+8) = s4[1];
    *(uint4*)(dst+16) = s4[2]; *(uint4*)(dst+24) = s4[3];
  }
  #pragma unroll
  for (int j = 0; j < 32; ++j) tile[(c + j) * 72 + r] = bf[j];
  cpart += __shfl_xor(cpart, 1);
  cpart += __shfl_xor(cpart, 2);
  if (cc == 0) colB[b * NSEM + n0 + r] = cpart;
  __syncthreads();

  const int d = tid >> 1, nh = (tid & 1) * 32;
  uint4 t0v = *(const uint4*)&tile[d * 72 + nh];
  uint4 t1v = *(const uint4*)&tile[d * 72 + nh + 8];
  uint4 t2v = *(const uint4*)&tile[d * 72 + nh + 16];
  uint4 t3v = *(const uint4*)&tile[d * 72 + nh + 24];
  const int n = n0 + nh;
  const int piece = n >> 9;
  unsigned short* dst = outw + ((size_t)(b * TT + d * 4 + piece)) * ORS + 512 + (n & 511);
  *(uint4*)(dst) = t0v; *(uint4*)(dst+8) = t1v;
  *(uint4*)(dst+16) = t2v; *(uint4*)(dst+24) = t3v;
}

// ---------------- kernel 2: flash, no-rescale softmax, 2-wave n-split ----------------
// grid = BSZ*128 blocks (b = bx>>7, t0 = (bx&127)*16), 128 thr = 2 waves.
// launch_bounds (128,2): 256-VGPR cap — round 6's (128,4) forced 64 VGPRs and
// spilled ~13 dwords/lane/iter to scratch (WRITE_SIZE 229 MB). Do not tighten.
__global__ __launch_bounds__(128, 2) void flash_kernel(const float* __restrict__ aud,
                                                       const float* __restrict__ W,
                                                       const float* __restrict__ colB,
                                                       float* __restrict__ m_ws,
                                                       float* __restrict__ outf,
                                                       const unsigned short* __restrict__ outw){
  __shared__ alignas(16) unsigned short pbuf[2][16 * PSTR];   // per-wave P staging
  __shared__ alignas(16) float obuf[16][132];                  // wave-1 partial O (padded)
  __shared__ float lmbuf[32];                                  // l[16], m[16]

  const int tid  = threadIdx.x;
  const int wv   = tid >> 6;
  const int lane = tid & 63;
  const int quad = lane >> 4;
  const int l15  = lane & 15;
  const int b    = blockIdx.x >> 7;
  const int t0   = (blockIdx.x & 127) * 16;

  // q A-frags (aud*w3 -> bf16) + rowA partial (fp32 dot aud,w1)
  const float* audRow = aud + ((size_t)b * TT + t0 + l15) * DIM;
  short8 qf[4];
  float rowA_part = 0.f;
  #pragma unroll
  for (int kc = 0; kc < 4; ++kc){
    int d0 = kc * 32 + quad * 8;
    float av[8], w3v[8], w1v[8];
    ld8f(audRow + d0, av);
    ld8f(W + 2 * DIM + d0, w3v);
    ld8f(W + d0, w1v);
    alignas(16) unsigned short tmp[8];
    #pragma unroll
    for (int j = 0; j < 8; ++j){
      tmp[j] = f2bf(av[j] * w3v[j]);
      rowA_part += av[j] * w1v[j];
    }
    qf[kc] = *(const short8*)tmp;
  }
  rowA_part += __shfl_xor(rowA_part, 16);
  rowA_part += __shfl_xor(rowA_part, 32);

  float m_l[4], l_l[4];
  floatx4 o[8];
  #pragma unroll
  for (int r = 0; r < 4; ++r){ m_l[r] = -1e30f; l_l[r] = 0.f; }
  #pragma unroll
  for (int dc = 0; dc < 8; ++dc){
    #pragma unroll
    for (int r = 0; r < 4; ++r) o[dc][r] = 0.f;
  }

  const unsigned short* semBF = outw + (size_t)b * TT * ORS;
  const float* colBb = colB + b * NSEM;
  unsigned short* pb = &pbuf[wv][0];
  const int nbeg = wv * 1024, nend = nbeg + 1024;

  for (int n0 = nbeg; n0 < nend; n0 += 64){
    // ---- QK: S = q . sem^T, 4 subtiles of 16 n ----
    floatx4 sacc[4];
    #pragma unroll
    for (int s = 0; s < 4; ++s){ sacc[s][0]=0.f; sacc[s][1]=0.f; sacc[s][2]=0.f; sacc[s][3]=0.f; }
    #pragma unroll
    for (int s = 0; s < 4; ++s){
      const unsigned short* kr = semBF + (size_t)(n0 + s*16 + l15) * ORS + quad * 8;
      #pragma unroll
      for (int kc = 0; kc < 4; ++kc){
        short8 kf = *(const short8*)(kr + kc * 32);
        sacc[s] = __builtin_amdgcn_mfma_f32_16x16x32_bf16(qf[kc], kf, sacc[s], 0, 0, 0);
      }
    }

    // ---- prefetch V-frags for kt=0 (overlaps the softmax VALU below) ----
    short8 vf0[8];
    {
      int nA = n0 + quad * 8;
      int pieceA = nA >> 9, ninA = nA & 511;
      #pragma unroll
      for (int dc = 0; dc < 8; ++dc)
        vf0[dc] = *(const short8*)(outw +
          ((size_t)(b * TT + (dc*16 + l15) * 4 + pieceA)) * ORS + 512 + ninA);
    }

    // ---- softmax (no rescale: e = exp(S), per-lane l/m accumulators) ----
    float cb[4];
    #pragma unroll
    for (int s = 0; s < 4; ++s) cb[s] = colBb[n0 + s*16 + l15];
    #pragma unroll
    for (int r = 0; r < 4; ++r){
      float v0 = sacc[0][r] + cb[0];
      float v1 = sacc[1][r] + cb[1];
      float v2 = sacc[2][r] + cb[2];
      float v3 = sacc[3][r] + cb[3];
      m_l[r] = fmaxf(m_l[r], fmaxf(fmaxf(v0, v1), fmaxf(v2, v3)));
      float e0 = __expf(v0), e1 = __expf(v1);
      float e2 = __expf(v2), e3 = __expf(v3);
      l_l[r] += (e0 + e1) + (e2 + e3);
      unsigned short* pr = pb + (quad*4 + r) * PSTR + l15;
      pr[0]  = f2bf(e0);
      pr[16] = f2bf(e1);
      pr[32] = f2bf(e2);
      pr[48] = f2bf(e3);
    }

    // wave-local LDS drain (DS pipe is in-order per wave; no block barrier needed)
    asm volatile("s_waitcnt lgkmcnt(0)" ::: "memory");
    short8 pf0 = *(const short8*)(pb + l15 * PSTR + quad * 8);
    short8 pf1 = *(const short8*)(pb + l15 * PSTR + 32 + quad * 8);

    // ---- PV: O += P . sem ----
    #pragma unroll
    for (int dc = 0; dc < 8; ++dc)
      o[dc] = __builtin_amdgcn_mfma_f32_16x16x32_bf16(pf0, vf0[dc], o[dc], 0, 0, 0);
    {
      int nB = n0 + 32 + quad * 8;
      int pieceB = nB >> 9, ninB = nB & 511;
      #pragma unroll
      for (int dc = 0; dc < 8; ++dc){
        short8 vf = *(const short8*)(outw +
          ((size_t)(b * TT + (dc*16 + l15) * 4 + pieceB)) * ORS + 512 + ninB);
        o[dc] = __builtin_amdgcn_mfma_f32_16x16x32_bf16(pf1, vf, o[dc], 0, 0, 0);
      }
    }
  }

  // ---- cross-lane reduce l/m within each quad (rows quad*4+r) ----
  #pragma unroll
  for (int r = 0; r < 4; ++r){
    float lv = l_l[r], mv = m_l[r];
    lv += __shfl_xor(lv, 1);  mv = fmaxf(mv, __shfl_xor(mv, 1));
    lv += __shfl_xor(lv, 2);  mv = fmaxf(mv, __shfl_xor(mv, 2));
    lv += __shfl_xor(lv, 4);  mv = fmaxf(mv, __shfl_xor(mv, 4));
    lv += __shfl_xor(lv, 8);  mv = fmaxf(mv, __shfl_xor(mv, 8));
    l_l[r] = lv; m_l[r] = mv;
  }

  // ---- merge wave 1 into wave 0 (additive; exp values are absolute) ----
  if (wv == 1){
    #pragma unroll
    for (int dc = 0; dc < 8; ++dc)
      #pragma unroll
      for (int r = 0; r < 4; ++r)
        obuf[quad*4 + r][dc*16 + l15] = o[dc][r];
    if (l15 == 0){
      #pragma unroll
      for (int r = 0; r < 4; ++r){
        lmbuf[quad*4 + r]      = l_l[r];
        lmbuf[16 + quad*4 + r] = m_l[r];
      }
    }
  }
  __syncthreads();
  if (wv == 0){
    #pragma unroll
    for (int r = 0; r < 4; ++r){
      l_l[r] += lmbuf[quad*4 + r];
      m_l[r] = fmaxf(m_l[r], lmbuf[16 + quad*4 + r]);
    }
    #pragma unroll
    for (int dc = 0; dc < 8; ++dc)
      #pragma unroll
      for (int r = 0; r < 4; ++r)
        o[dc][r] += obuf[quad*4 + r][dc*16 + l15];

    float rl[4];
    #pragma unroll
    for (int r = 0; r < 4; ++r) rl[r] = 1.0f / l_l[r];
    float* outB = outf + ((size_t)b * TT + t0) * 512 + 128;   // seg1
    #pragma unroll
    for (int dc = 0; dc < 8; ++dc)
      #pragma unroll
      for (int r = 0; r < 4; ++r)
        outB[(size_t)(quad*4 + r) * 512 + dc*16 + l15] = o[dc][r] * rl[r];

    float rAr[4];
    #pragma unroll
    for (int r = 0; r < 4; ++r) rAr[r] = __shfl(rowA_part, quad*4 + r);
    if (l15 == 0){
      #pragma unroll
      for (int r = 0; r < 4; ++r)
        m_ws[(size_t)b * TT + t0 + quad*4 + r] = m_l[r] + rAr[r];
    }
  }
}

// ---------------- kernel 3a: per-chunk max of m ----------------
__global__ __launch_bounds__(256) void bw1_kernel(const float* __restrict__ m_ws,
                                                  float* __restrict__ pmax){
  __shared__ float sA[4];
  const int b = blockIdx.x >> 3, ch = blockIdx.x & 7, tid = threadIdx.x;
  float v = m_ws[(size_t)b * TT + ch * 256 + tid];
  #pragma unroll
  for (int off = 1; off < 64; off <<= 1) v = fmaxf(v, __shfl_xor(v, off));
  if ((tid & 63) == 0) sA[tid >> 6] = v;
  __syncthreads();
  if (tid == 0)
    pmax[blockIdx.x] = fmaxf(fmaxf(sA[0], sA[1]), fmaxf(sA[2], sA[3]));
}

// ---------------- kernel 3b: partial exp-sum + partial a2 ----------------
__global__ __launch_bounds__(256) void bw2_kernel(const float* __restrict__ aud,
                                                  const float* __restrict__ m_ws,
                                                  const float* __restrict__ pmax,
                                                  float* __restrict__ gpart,
                                                  float* __restrict__ part){
  __shared__ float wbuf[256];
  __shared__ float red[16 * 128];
  __shared__ float gs4[4];
  const int b = blockIdx.x >> 3, ch = blockIdx.x & 7, tid = threadIdx.x;

  float gmax = pmax[b * 8];
  #pragma unroll
  for (int i = 1; i < 8; ++i) gmax = fmaxf(gmax, pmax[b * 8 + i]);

  float w = __expf(m_ws[(size_t)b * TT + ch * 256 + tid] - gmax);
  wbuf[tid] = w;
  float sm = w;
  #pragma unroll
  for (int off = 1; off < 64; off <<= 1) sm += __shfl_xor(sm, off);
  if ((tid & 63) == 0) gs4[tid >> 6] = sm;
  __syncthreads();
  if (tid == 0) gpart[blockIdx.x] = (gs4[0] + gs4[1]) + (gs4[2] + gs4[3]);

  const int dg = tid & 15, q = tid >> 4;
  float acc[8] = {0,0,0,0,0,0,0,0};
  const float* ab = aud + ((size_t)b * TT + ch * 256 + q * 16) * DIM + dg * 8;
  for (int i = 0; i < 16; ++i){
    float av[8];
    ld8f(ab + (size_t)i * DIM, av);
    float wt = wbuf[q * 16 + i];
    #pragma unroll
    for (int j = 0; j < 8; ++j) acc[j] += wt * av[j];
  }
  #pragma unroll
  for (int j = 0; j < 8; ++j) red[q * 128 + dg * 8 + j] = acc[j];
  __syncthreads();
  if (tid < 128){
    float s = 0.f;
    #pragma unroll
    for (int q2 = 0; q2 < 16; ++q2) s += red[q2 * 128 + tid];
    part[(size_t)blockIdx.x * 128 + tid] = s;
  }
}

// ---------------- kernel 3c: combine partials -> normalized a2 ----------------
__global__ __launch_bounds__(128) void bw3_kernel(const float* __restrict__ gpart,
                                                  const float* __restrict__ part,
                                                  float* __restrict__ a2_ws){
  const int b = blockIdx.x, d = threadIdx.x;
  float s = 0.f, g = 0.f;
  #pragma unroll
  for (int ch = 0; ch < 8; ++ch){
    s += part[(size_t)(b * 8 + ch) * 128 + d];
    g += gpart[b * 8 + ch];
  }
  a2_ws[b * DIM + d] = s / g;
}

// ---------------- kernel 4: read seg1 (h), write seg0/2/3 ----------------
__global__ __launch_bounds__(256) void epi_kernel(const float* __restrict__ aud,
                                                  const float* __restrict__ a2_ws,
                                                  float* __restrict__ out){
  int id = blockIdx.x * 256 + threadIdx.x;        // BSZ*TT*16
  int c = id & 15;
  int t = (id >> 4) & (TT - 1);
  int b = id >> 15;
  size_t row = (size_t)b * TT + t;

  float av[8], gv[8], hv[8];
  ld8f(aud + row * DIM + c * 8, av);
  ld8f(a2_ws + b * DIM + c * 8, gv);
  ld8f(out + row * 512 + 128 + c * 8, hv);        // h (seg1)

  floatx4 o0a, o0b, o2a, o2b, o3a, o3b;
  #pragma unroll
  for (int j = 0; j < 4; ++j){
    o0a[j] = av[j];           o0b[j] = av[4+j];
    o2a[j] = av[j]*hv[j];     o2b[j] = av[4+j]*hv[4+j];
    o3a[j] = av[j]*gv[j];     o3b[j] = av[4+j]*gv[4+j];
  }
  float* ob = out + row * 512 + c * 8;
  *(floatx4*)(ob)       = o0a;  *(floatx4*)(ob + 4)   = o0b;   // seg0: aud
  *(floatx4*)(ob + 256) = o2a;  *(floatx4*)(ob + 260) = o2b;   // seg2: aud*h
  *(floatx4*)(ob + 384) = o3a;  *(floatx4*)(ob + 388) = o3b;   // seg3: aud*a2
}

extern "C" void kernel_launch(void* const* d_in, const int* in_sizes, int n_in,
                              void* d_out, int out_size, void* d_ws, size_t ws_size,
                              hipStream_t stream){
  const float* aud = (const float*)d_in[0];   // fp32 inputs (verified round 4)
  const float* sem = (const float*)d_in[1];
  const float* W   = (const float*)d_in[2];
  // d_in[3] (bias) cancels in both softmaxes.
  float* out = (float*)d_out;                 // fp32 output (verified round 4)
  unsigned short* outw = (unsigned short*)d_out;

  float* ws    = (float*)d_ws;
  float* m_ws  = ws;                                   // 32768 f (128 KB)
  float* colB  = m_ws + (size_t)BSZ * TT;              // 32768 f (128 KB)
  float* a2_ws = colB + (size_t)BSZ * NSEM;            // 2048 f  (8 KB)
  float* pmax  = a2_ws + BSZ * DIM;                    // 128 f
  float* gpart = pmax + 128;                           // 128 f
  float* part  = gpart + 128;                          // 16384 f (64 KB)

  prep_kernel <<<512, 256, 0, stream>>>(sem, W, colB, outw);
  flash_kernel<<<BSZ * 128, 128, 0, stream>>>(aud, W, colB, m_ws, out, outw);
  bw1_kernel  <<<128, 256, 0, stream>>>(m_ws, pmax);
  bw2_kernel  <<<128, 256, 0, stream>>>(aud, m_ws, pmax, gpart, part);
  bw3_kernel  <<<BSZ, 128, 0, stream>>>(gpart, part, a2_ws);
  epi_kernel  <<<(BSZ * TT * 16) / 256, 256, 0, stream>>>(aud, a2_ws, out);
}